// Round 8
// baseline (354.156 us; speedup 1.0000x reference)
//
#include <hip/hip_runtime.h>

typedef unsigned short u16;
typedef unsigned int   u32;
typedef __attribute__((ext_vector_type(4))) float f32x4;
typedef __attribute__((ext_vector_type(8))) short s16x8;
typedef __attribute__((ext_vector_type(4))) unsigned short u16x4;
typedef __attribute__((ext_vector_type(8))) unsigned short u16x8;

#define HW    36864
#define NCH   256
#define NB    4
#define NPIX  147456
#define POS   85
#define BN_EPS 1e-5f
#define NBKT  16

// ---- workspace float offsets ----
#define WS_P3      0            // u32 leaf maxes [b][c][64]
#define WS_PALL    65536        // 87040
#define WS_YD      152576       // 87040
#define WS_PSUM    239616       // 1024
#define WS_PSQ     240640       // 1024
#define WS_CONTRIB 241664       // 65536  C[b][o][cell]
#define WS_S1      307200       // 65536  S1[b][o][cell]
#define WS_FSQB    372736       // 4096   [bkt][o]
#define WS_SC      376832       // 256
#define WS_ADD     377088       // 65536  add[b][o][cell]
#define WS_WPK     442624       // u16[65536] = 32768 floats
#define WS_YBF     475392       // u16 y: 18874368 floats
#define WS_TOT1    (WS_YBF + NB*NCH*HW/2)

__device__ __forceinline__ u16 f2bf(float f) {
  u32 u = __builtin_bit_cast(u32, f);
  u += 0x7fffu + ((u >> 16) & 1u);
  return (u16)(u >> 16);
}
__device__ __forceinline__ float bf2f(u16 h) {
  u32 u = ((u32)h) << 16;
  return __builtin_bit_cast(float, u);
}
// monotone float<->u32 encoding (0 == smaller-than-any-finite sentinel)
__device__ __forceinline__ u32 encf(float f) {
  u32 b = __builtin_bit_cast(u32, f);
  return (b & 0x80000000u) ? ~b : (b | 0x80000000u);
}
__device__ __forceinline__ float decf(u32 k) {
  u32 b = (k & 0x80000000u) ? (k & 0x7fffffffu) : ~k;
  return __builtin_bit_cast(float, b);
}

// K0: blocks 0..31 pack wf[:, :256] -> bf16 A-frags; blocks 32..287 zero accumulators
__global__ __launch_bounds__(256) void k_wpack(const float* __restrict__ wf, float* __restrict__ wsb) {
  int blk = blockIdx.x, t = threadIdx.x;
  if (blk >= 32) {
    int id = (blk - 32)*256 + t;             // 0..65535
    wsb[WS_P3 + id] = 0.f;
    wsb[WS_S1 + id] = 0.f;
    if (id < 4096) wsb[WS_FSQB + id] = 0.f;
    if (id < 2048) wsb[WS_PSUM + id] = 0.f;  // PSUM+PSQ contiguous
    return;
  }
  int fid = blk*256 + t;                     // [ks32][g][m]
  int m = fid & 255, g = (fid >> 8) & 3, ks = fid >> 10;
  const float* src = wf + (size_t)m*1280 + ks*32 + g*8;
  f32x4 a = *(const f32x4*)src;
  f32x4 c = *(const f32x4*)(src + 4);
  u32* dst = (u32*)((u16*)(wsb + WS_WPK) + (size_t)fid*8);
  dst[0] = (u32)f2bf(a.x) | ((u32)f2bf(a.y) << 16);
  dst[1] = (u32)f2bf(a.z) | ((u32)f2bf(a.w) << 16);
  dst[2] = (u32)f2bf(c.x) | ((u32)f2bf(c.y) << 16);
  dst[3] = (u32)f2bf(c.z) | ((u32)f2bf(c.w) << 16);
}

// K1: main GEMM (pure) + fused leaf-max pooling + S1/sumsq stats + bf16 y.
template<bool YBF>
__global__ __launch_bounds__(256, 3) void k_main(const float* __restrict__ x,
                                                 float* __restrict__ wsb, float* __restrict__ y) {
  __shared__ __align__(16) u32 xbuf[2][64*20];   // 10 KB
  __shared__ u32 pmaxl[256*4];                   // 4 KB  [ch][cellLocal]
  __shared__ __align__(16) u16 ytile[128*72];    // 18 KB
  int wg = blockIdx.x;
  int b = wg / 576, tile = wg % 576;
  int n0 = tile * 64;
  int row = tile / 3;
  int t = threadIdx.x, w = t >> 6, l = t & 63, g = l >> 4, ln = l & 15;
  int cb0 = (tile % 3) * 64;
  int cblk0 = cb0 / 24;
  int maxcl = (cb0 + 63)/24 - cblk0;
  int cellbase = (row/24)*8 + cblk0;
  const u16* wpk = (const u16*)(wsb + WS_WPK);
  int mrow = w*64 + ln;
  int qq = t & 15, c2 = t >> 4;                  // staging: px-quad, channel-pair
  int cellLoc = (cb0 + 4*qq)/24 - cblk0;         // this thread's px-quad cell (never straddles)
  const float* xsrc = x + (size_t)(b*NCH + 2*c2)*HW + n0 + 4*qq;

  // init pooling table
  #pragma unroll
  for (int j = 0; j < 4; j++) pmaxl[t*4 + j] = 0u;

  // prologue: x loads slabs 0..3 (8 loads in flight)
  f32x4 xa[4], xbv[4];
  #pragma unroll
  for (int i = 0; i < 4; i++) {
    xa[i]  = *(const f32x4*)(xsrc + (size_t)(i*32)*HW);
    xbv[i] = *(const f32x4*)(xsrc + (size_t)(i*32 + 1)*HW);
  }
  // W-frag double buffer; prefetch slab 0
  s16x8 af[2][4];
  #pragma unroll
  for (int tm = 0; tm < 4; tm++)
    af[0][tm] = *(const s16x8*)(wpk + ((size_t)g*256 + mrow + tm*16)*8);

  asm volatile("s_waitcnt lgkmcnt(0)" ::: "memory");
  __builtin_amdgcn_s_barrier();
  __builtin_amdgcn_sched_barrier(0);

  f32x4 acc[4][4];
  #pragma unroll
  for (int i = 0; i < 4; i++)
    #pragma unroll
    for (int j = 0; j < 4; j++)
      acc[i][j] = {0.f, 0.f, 0.f, 0.f};

  int slot = (((c2 >> 2) ^ (qq & 3)) << 2) | (c2 & 3);   // group-XOR swizzle

  #pragma unroll
  for (int i = 0; i < 8; i++) {
    // stage slab i (counted vmcnt by compiler) + fused pooling on fp32 values
    {
      u32* dst = &xbuf[i & 1][0];
      f32x4 va = xa[i & 3], vb = xbv[i & 3];
      #pragma unroll
      for (int j = 0; j < 4; j++) {
        u32 pk = (u32)f2bf(va[j]) | ((u32)f2bf(vb[j]) << 16);
        dst[(4*qq + j)*20 + slot] = pk;
      }
      float ma = fmaxf(fmaxf(va.x, va.y), fmaxf(va.z, va.w));
      float mb = fmaxf(fmaxf(vb.x, vb.y), fmaxf(vb.z, vb.w));
      int ca = 2*c2 + 32*i;
      atomicMax(&pmaxl[ca*4 + cellLoc], encf(ma));
      atomicMax(&pmaxl[(ca + 1)*4 + cellLoc], encf(mb));
    }
    asm volatile("s_waitcnt lgkmcnt(0)" ::: "memory");
    __builtin_amdgcn_s_barrier();
    __builtin_amdgcn_sched_barrier(0);
    // prefetch x slab i+4
    if (i < 4) {
      xa[i & 3]  = *(const f32x4*)(xsrc + (size_t)((i+4)*32)*HW);
      xbv[i & 3] = *(const f32x4*)(xsrc + (size_t)((i+4)*32 + 1)*HW);
    }
    // prefetch W-frags slab i+1
    if (i < 7) {
      #pragma unroll
      for (int tm = 0; tm < 4; tm++)
        af[(i+1) & 1][tm] = *(const s16x8*)(wpk + ((size_t)((i+1)*4 + g)*256 + mrow + tm*16)*8);
    }
    // compute slab i
    #pragma unroll
    for (int tn = 0; tn < 4; tn++) {
      int px = 16*tn + ln;
      int gr = g ^ ((px >> 2) & 3);
      s16x8 bfr = *(const s16x8*)((const u16*)&xbuf[i & 1][px*20 + gr*4]);
      #pragma unroll
      for (int tm = 0; tm < 4; tm++)
        acc[tm][tn] = __builtin_amdgcn_mfma_f32_16x16x32_bf16(af[i & 1][tm], bfr, acc[tm][tn], 0, 0, 0);
    }
  }

  // ---- flush pooling table (staging atomics all complete: last loop barrier) ----
  {
    u32* P3g = (u32*)(wsb + WS_P3) + ((size_t)(b*NCH + t))*64 + cellbase;
    #pragma unroll
    for (int j = 0; j < 4; j++) {
      if (j <= maxcl) { u32 v = pmaxl[t*4 + j]; if (v) atomicMax(&P3g[j], v); }
    }
  }

  int bkt = wg & (NBKT - 1);
  float* fsqb = wsb + WS_FSQB + bkt*256;
  float* S1g  = wsb + WS_S1 + ((size_t)b*NCH)*64;

  if (YBF) {
    u16* ybb = (u16*)(wsb + WS_YBF) + (size_t)b*NCH*HW + n0;
    #pragma unroll
    for (int half = 0; half < 2; half++) {
      if ((w >> 1) == half) {
        #pragma unroll
        for (int tm = 0; tm < 4; tm++)
          #pragma unroll
          for (int r = 0; r < 4; r++) {
            int orow = (w & 1)*64 + tm*16 + g*4 + r;
            #pragma unroll
            for (int tn = 0; tn < 4; tn++)
              ytile[orow*72 + 16*tn + ln] = f2bf(acc[tm][tn][r]);
          }
      }
      __syncthreads();
      int oo = t >> 3, seg = t & 7;
      int basec = cb0 + seg*8;
      int loG = basec/24, hiG = (basec + 7)/24;
      int kk = (loG + 1)*24 - basec; if (kk > 8) kk = 8;
      int lo = loG - cblk0, hi = hiG - cblk0;
      #pragma unroll
      for (int r8 = 0; r8 < 4; r8++) {
        int ol = r8*32 + oo;
        int o  = half*128 + ol;
        u16x8 v = *(const u16x8*)&ytile[ol*72 + seg*8];
        *(u16x8*)(ybb + (size_t)o*HW + seg*8) = v;
        float p_lo = 0.f, p_hi = 0.f, s2p = 0.f;
        #pragma unroll
        for (int e = 0; e < 8; e++) {
          float yr = bf2f(v[e]);
          s2p += yr*yr;
          if (e < kk) p_lo += yr; else p_hi += yr;
        }
        s2p += __shfl_xor(s2p, 1); s2p += __shfl_xor(s2p, 2); s2p += __shfl_xor(s2p, 4);
        if (seg == 0) atomicAdd(&fsqb[o], s2p);
        float* S1o = S1g + (size_t)o*64 + cellbase;
        #pragma unroll
        for (int cl = 0; cl < 4; cl++) {
          float val = (lo == cl ? p_lo : 0.f) + (hi == cl ? p_hi : 0.f);
          val += __shfl_xor(val, 1); val += __shfl_xor(val, 2); val += __shfl_xor(val, 4);
          if (seg == cl && cl <= maxcl) atomicAdd(&S1o[cl], val);
        }
      }
      __syncthreads();
    }
  } else {
    float* yf = y + (size_t)b*NCH*HW + n0;
    #pragma unroll
    for (int tm = 0; tm < 4; tm++) {
      #pragma unroll
      for (int r = 0; r < 4; r++) {
        int o = w*64 + tm*16 + g*4 + r;
        float s1c0 = 0.f, s1c1 = 0.f, s1c2 = 0.f, s1c3 = 0.f, s2 = 0.f;
        #pragma unroll
        for (int tn = 0; tn < 4; tn++) {
          int px = 16*tn + ln;
          float v = acc[tm][tn][r];
          yf[(size_t)o*HW + px] = v;
          int ci = (cb0 + px)/24 - cblk0;
          s1c0 += (ci == 0) ? v : 0.f;
          s1c1 += (ci == 1) ? v : 0.f;
          s1c2 += (ci == 2) ? v : 0.f;
          s1c3 += (ci == 3) ? v : 0.f;
          s2 += v*v;
        }
        s2 += __shfl_xor(s2, 1); s2 += __shfl_xor(s2, 2);
        s2 += __shfl_xor(s2, 4); s2 += __shfl_xor(s2, 8);
        if (ln == 0) atomicAdd(&fsqb[o], s2);
        float* S1o = S1g + (size_t)o*64 + cellbase;
        float sv[4] = {s1c0, s1c1, s1c2, s1c3};
        #pragma unroll
        for (int cl = 0; cl < 4; cl++) {
          float val = sv[cl];
          val += __shfl_xor(val, 1); val += __shfl_xor(val, 2);
          val += __shfl_xor(val, 4); val += __shfl_xor(val, 8);
          if (ln == cl && cl <= maxcl) atomicAdd(&S1o[cl], val);
        }
      }
    }
  }
}

// K2: decode leaves -> 85-entry pyramids per (b,c)
__global__ __launch_bounds__(64) void k_ppyr(float* __restrict__ wsb) {
  __shared__ float sm3[64], sm2[16], sm1[4];
  int bc = blockIdx.x;
  int t = threadIdx.x;
  const u32* p3 = (const u32*)(wsb + WS_P3) + (size_t)bc*64;
  float leaf = decf(p3[t]);
  sm3[t] = leaf;
  __syncthreads();
  float* pb = wsb + WS_PALL + (size_t)bc*POS;
  pb[t] = leaf;
  if (t < 16) {
    int i = t >> 2, j = t & 3;
    float m = fmaxf(fmaxf(sm3[(2*i)*8 + 2*j], sm3[(2*i)*8 + 2*j + 1]),
                    fmaxf(sm3[(2*i+1)*8 + 2*j], sm3[(2*i+1)*8 + 2*j + 1]));
    sm2[t] = m; pb[64 + t] = m;
  }
  __syncthreads();
  if (t < 4) {
    int i = t >> 1, j = t & 1;
    float m = fmaxf(fmaxf(sm2[(2*i)*4 + 2*j], sm2[(2*i)*4 + 2*j + 1]),
                    fmaxf(sm2[(2*i+1)*4 + 2*j], sm2[(2*i+1)*4 + 2*j + 1]));
    sm1[t] = m; pb[80 + t] = m;
  }
  __syncthreads();
  if (t == 0)
    pb[84] = fmaxf(fmaxf(sm1[0], sm1[1]), fmaxf(sm1[2], sm1[3]));
}

// K3: pyramid convs on distinct block values + BN stat accumulation
__global__ __launch_bounds__(256) void k_pyr(const float* __restrict__ wconv, float* __restrict__ wsb) {
  __shared__ __align__(16) float pv[256];
  int bi = blockIdx.x;                       // b*85 + pos
  int b = bi / 85, pos = bi % 85;
  int d = (pos < 64) ? 3 : (pos < 80) ? 2 : (pos < 84) ? 1 : 0;
  int t = threadIdx.x;
  pv[t] = wsb[WS_PALL + (size_t)(b*NCH + t)*POS + pos];
  __syncthreads();
  const float* wrow = wconv + ((size_t)d*NCH + t)*NCH;
  float acc = 0.f;
  #pragma unroll 4
  for (int c4 = 0; c4 < 64; c4++) {
    f32x4 wv = *(const f32x4*)(wrow + c4*4);
    f32x4 xv = *(const f32x4*)(&pv[c4*4]);
    acc += wv.x*xv.x + wv.y*xv.y + wv.z*xv.z + wv.w*xv.w;
  }
  wsb[WS_YD + (size_t)(b*NCH + t)*POS + pos] = acc;
  atomicAdd(&wsb[WS_PSUM + d*NCH + t], acc);
  atomicAdd(&wsb[WS_PSQ  + d*NCH + t], acc*acc);
}

// K4: contrib C[b][o][cell] = sum over all 4 depths (no atomics; grid = 64 cells)
__global__ __launch_bounds__(256) void k_contrib(const float* __restrict__ wf,
                                                 const float* __restrict__ gs,
                                                 const float* __restrict__ bs,
                                                 float* __restrict__ wsb) {
  __shared__ __align__(16) float pn[16][256];   // [d*4+b][c]
  int cell = blockIdx.x;
  int by = cell >> 3, bx = cell & 7;
  int t = threadIdx.x;
  #pragma unroll
  for (int d = 0; d < 4; d++) {
    int pos = (d == 3) ? cell
            : (d == 2) ? 64 + (by >> 1)*4 + (bx >> 1)
            : (d == 1) ? 80 + (by >> 2)*2 + (bx >> 2)
            : 84;
    float cnt = (float)(4 << (2*d));
    float mu  = wsb[WS_PSUM + d*NCH + t] / cnt;
    float var = wsb[WS_PSQ  + d*NCH + t] / cnt - mu*mu;
    float sc  = gs[d*NCH + t] * rsqrtf(var + BN_EPS);
    float bi_ = bs[d*NCH + t] - mu * sc;
    #pragma unroll
    for (int b = 0; b < 4; b++)
      pn[d*4 + b][t] = wsb[WS_YD + (size_t)(b*NCH + t)*POS + pos] * sc + bi_;
  }
  __syncthreads();
  float a0 = 0.f, a1 = 0.f, a2 = 0.f, a3 = 0.f;
  #pragma unroll
  for (int d = 0; d < 4; d++) {
    const float* wrow = wf + (size_t)t*1280 + 256 + d*256;
    #pragma unroll 4
    for (int j = 0; j < 64; j++) {
      f32x4 wv = *(const f32x4*)(wrow + j*4);
      f32x4 p0 = *(const f32x4*)(&pn[d*4 + 0][j*4]);
      f32x4 p1 = *(const f32x4*)(&pn[d*4 + 1][j*4]);
      f32x4 p2 = *(const f32x4*)(&pn[d*4 + 2][j*4]);
      f32x4 p3 = *(const f32x4*)(&pn[d*4 + 3][j*4]);
      a0 += wv.x*p0.x + wv.y*p0.y + wv.z*p0.z + wv.w*p0.w;
      a1 += wv.x*p1.x + wv.y*p1.y + wv.z*p1.z + wv.w*p1.w;
      a2 += wv.x*p2.x + wv.y*p2.y + wv.z*p2.z + wv.w*p2.w;
      a3 += wv.x*p3.x + wv.y*p3.y + wv.z*p3.z + wv.w*p3.w;
    }
  }
  wsb[WS_CONTRIB + (size_t)(0*NCH + t)*64 + cell] = a0;
  wsb[WS_CONTRIB + (size_t)(1*NCH + t)*64 + cell] = a1;
  wsb[WS_CONTRIB + (size_t)(2*NCH + t)*64 + cell] = a2;
  wsb[WS_CONTRIB + (size_t)(3*NCH + t)*64 + cell] = a3;
}

// K5: final BN stats via decomposition; emit sc[o] and add[b][o][cell]
__global__ __launch_bounds__(256) void k_fstats(const float* __restrict__ gf,
                                                const float* __restrict__ bfv,
                                                float* __restrict__ wsb) {
  int o = threadIdx.x;
  float sq = 0.f;
  #pragma unroll
  for (int i = 0; i < NBKT; i++) sq += wsb[WS_FSQB + i*256 + o];
  float sum1 = 0.f, sum2 = sq;
  #pragma unroll 8
  for (int bc = 0; bc < 256; bc++) {
    int b = bc >> 6, cell = bc & 63;
    float s1 = wsb[WS_S1      + ((size_t)(b*NCH + o))*64 + cell];
    float c  = wsb[WS_CONTRIB + ((size_t)(b*NCH + o))*64 + cell];
    sum1 += s1 + 576.f*c;
    sum2 += c*(2.f*s1 + 576.f*c);
  }
  float inv = 1.f / (float)NPIX;
  float mu  = sum1 * inv;
  float var = sum2 * inv - mu*mu;
  float sc  = gf[o] * rsqrtf(var + BN_EPS);
  float bi  = bfv[o] - mu * sc;
  wsb[WS_SC + o] = sc;
  #pragma unroll 8
  for (int bc = 0; bc < 256; bc++) {
    int b = bc >> 6, cell = bc & 63;
    float c = wsb[WS_CONTRIB + ((size_t)(b*NCH + o))*64 + cell];
    wsb[WS_ADD + ((size_t)(b*NCH + o))*64 + cell] = bi + c*sc;
  }
}

// K6: normalize: out = G*sc + add[b][o][cell]
template<bool YBF>
__global__ __launch_bounds__(256) void k_norm(float* __restrict__ out,
                                              const float* __restrict__ wsb) {
  __shared__ float a16[16];
  int bid = blockIdx.x;                      // plane*4 + quarter
  int plane = bid >> 2, q = bid & 3;         // plane = b*256 + o
  int t = threadIdx.x;
  float sc = wsb[WS_SC + (plane & 255)];
  if (t < 16)
    a16[t] = wsb[WS_ADD + (size_t)plane*64 + (2*q + (t >> 3))*8 + (t & 7)];
  __syncthreads();
  size_t base4 = ((size_t)plane*HW + q*(HW/4)) >> 2;   // f32x4 / u16x4 index
  if (YBF) {
    const u16* yb = (const u16*)(wsb + WS_YBF);
    #pragma unroll
    for (int it = 0; it < 9; it++) {
      int pl = 4*(it*256 + t);               // px within quarter
      int rl = pl / 192;
      int cc = (pl - rl*192) / 24;
      float ad = a16[(rl/24)*8 + cc];
      size_t i4 = base4 + it*256 + t;
      u16x4 v = *(const u16x4*)(yb + i4*4);
      f32x4 o;
      o.x = bf2f(v[0])*sc + ad;
      o.y = bf2f(v[1])*sc + ad;
      o.z = bf2f(v[2])*sc + ad;
      o.w = bf2f(v[3])*sc + ad;
      ((f32x4*)out)[i4] = o;
    }
  } else {
    #pragma unroll
    for (int it = 0; it < 9; it++) {
      int pl = 4*(it*256 + t);
      int rl = pl / 192;
      int cc = (pl - rl*192) / 24;
      float ad = a16[(rl/24)*8 + cc];
      size_t i4 = base4 + it*256 + t;
      f32x4 v = ((f32x4*)out)[i4];
      v.x = v.x*sc + ad; v.y = v.y*sc + ad; v.z = v.z*sc + ad; v.w = v.w*sc + ad;
      ((f32x4*)out)[i4] = v;
    }
  }
}

extern "C" void kernel_launch(void* const* d_in, const int* in_sizes, int n_in,
                              void* d_out, int out_size, void* d_ws, size_t ws_size,
                              hipStream_t stream) {
  const float* x  = (const float*)d_in[0];
  const float* w  = (const float*)d_in[1];
  const float* gs = (const float*)d_in[2];
  const float* bs = (const float*)d_in[3];
  const float* wf = (const float*)d_in[4];
  const float* gf = (const float*)d_in[5];
  const float* bf = (const float*)d_in[6];
  float* y   = (float*)d_out;
  float* wsb = (float*)d_ws;

  bool ybf = ws_size >= (size_t)WS_TOT1 * sizeof(float);

  k_wpack  <<<288, 256, 0, stream>>>(wf, wsb);
  if (ybf) k_main<true> <<<NB*576, 256, 0, stream>>>(x, wsb, y);
  else     k_main<false><<<NB*576, 256, 0, stream>>>(x, wsb, y);
  k_ppyr   <<<NB*NCH, 64, 0, stream>>>(wsb);
  k_pyr    <<<NB*POS, 256, 0, stream>>>(w, wsb);
  k_contrib<<<64, 256, 0, stream>>>(wf, gs, bs, wsb);
  k_fstats <<<1, 256, 0, stream>>>(gf, bf, wsb);
  if (ybf) k_norm<true> <<<4096, 256, 0, stream>>>(y, wsb);
  else     k_norm<false><<<4096, 256, 0, stream>>>(y, wsb);
}

// Round 9
// 198.453 us; speedup vs baseline: 1.7846x; 1.7846x over previous
//
#include <hip/hip_runtime.h>

typedef unsigned short u16;
typedef unsigned int   u32;
typedef __attribute__((ext_vector_type(4))) float f32x4;
typedef __attribute__((ext_vector_type(8))) short s16x8;
typedef __attribute__((ext_vector_type(4))) unsigned short u16x4;
typedef __attribute__((ext_vector_type(8))) unsigned short u16x8;

#define HW    36864
#define NCH   256
#define NB    4
#define NPIX  147456
#define POS   85
#define BN_EPS 1e-5f
#define NBKT  16

// ---- workspace float offsets ----
#define WS_PALL    0            // 4*256*85 = 87040
#define WS_YD      87040        // 87040
#define WS_PSUM    174080       // 1024
#define WS_PSQ     175104       // 1024
#define WS_CONTRIB 176128       // 65536 (non-atomic, no zeroing needed)
#define WS_FSUMB   241664       // 4096
#define WS_FSQB    245760       // 4096
#define WS_WPK     249856       // u16[65536] = 32768 floats
#define WS_YBF     282624       // u16 y: 18874368 floats
#define WS_TOT1    (WS_YBF + NB*NCH*HW/2)

__device__ __forceinline__ u16 f2bf(float f) {
  u32 u = __builtin_bit_cast(u32, f);
  u += 0x7fffu + ((u >> 16) & 1u);
  return (u16)(u >> 16);
}
__device__ __forceinline__ float bf2f(u16 h) {
  u32 u = ((u32)h) << 16;
  return __builtin_bit_cast(float, u);
}

// K1: blocks 0..1023: per-(b,c) plane -> 85-entry block-max pyramid (r2-proven).
//     blocks 1024..1067: pack wf[:, :256] -> bf16 A-frags (folded k_wpack).
__global__ __launch_bounds__(192) void k_pool(const float* __restrict__ x,
                                              const float* __restrict__ wf,
                                              float* __restrict__ wsb) {
  int blk = blockIdx.x;
  int t = threadIdx.x;
  if (blk >= 1024) {
    int fid = (blk - 1024)*192 + t;          // [ks32][g][m]
    if (fid < 8192) {
      int m = fid & 255, g = (fid >> 8) & 3, ks = fid >> 10;
      const float* src = wf + (size_t)m*1280 + ks*32 + g*8;
      f32x4 a = *(const f32x4*)src;
      f32x4 c = *(const f32x4*)(src + 4);
      u32* dst = (u32*)((u16*)(wsb + WS_WPK) + (size_t)fid*8);
      dst[0] = (u32)f2bf(a.x) | ((u32)f2bf(a.y) << 16);
      dst[1] = (u32)f2bf(a.z) | ((u32)f2bf(a.w) << 16);
      dst[2] = (u32)f2bf(c.x) | ((u32)f2bf(c.y) << 16);
      dst[3] = (u32)f2bf(c.z) | ((u32)f2bf(c.w) << 16);
    }
    return;
  }
  __shared__ float sm[8][4][48];
  __shared__ float sp[84];
  int bc = blk;                              // b*256 + c
  const float* base = x + (size_t)bc * HW;
  int cg = t % 48, rg = t / 48;
  if (bc == 0) {                             // zero stat accumulators
    for (int i = t; i < 2048; i += 192) wsb[WS_PSUM + i] = 0.f;
    for (int i = t; i < 8192; i += 192) wsb[WS_FSUMB + i] = 0.f;
  }
  #pragma unroll
  for (int byi = 0; byi < 8; byi++) {
    float mm = -3.4e38f;
    #pragma unroll
    for (int rr = 0; rr < 6; rr++) {
      int r = byi*24 + rg + 4*rr;
      f32x4 v = *(const f32x4*)(base + r*192 + cg*4);
      mm = fmaxf(mm, fmaxf(fmaxf(v.x, v.y), fmaxf(v.z, v.w)));
    }
    sm[byi][rg][cg] = mm;
  }
  __syncthreads();
  size_t pb = WS_PALL + (size_t)bc * POS;
  if (t < 64) {
    int by = t >> 3, bx = t & 7;
    float mm = -3.4e38f;
    for (int r2 = 0; r2 < 4; r2++)
      for (int cq = 0; cq < 6; cq++)
        mm = fmaxf(mm, sm[by][r2][bx*6 + cq]);
    sp[t] = mm;
    wsb[pb + t] = mm;
  }
  __syncthreads();
  if (t < 16) {
    int i = t >> 2, j = t & 3;
    float mm = fmaxf(fmaxf(sp[(2*i)*8 + 2*j], sp[(2*i)*8 + 2*j + 1]),
                     fmaxf(sp[(2*i+1)*8 + 2*j], sp[(2*i+1)*8 + 2*j + 1]));
    sp[64 + t] = mm;
    wsb[pb + 64 + t] = mm;
  }
  __syncthreads();
  if (t < 4) {
    int i = t >> 1, j = t & 1;
    float mm = fmaxf(fmaxf(sp[64 + (2*i)*4 + 2*j], sp[64 + (2*i)*4 + 2*j + 1]),
                     fmaxf(sp[64 + (2*i+1)*4 + 2*j], sp[64 + (2*i+1)*4 + 2*j + 1]));
    sp[80 + t] = mm;
    wsb[pb + 80 + t] = mm;
  }
  __syncthreads();
  if (t == 0)
    wsb[pb + 84] = fmaxf(fmaxf(sp[80], sp[81]), fmaxf(sp[82], sp[83]));
}

// K2: pyramid convs on distinct block values + BN stat accumulation
__global__ __launch_bounds__(256) void k_pyr(const float* __restrict__ wconv, float* __restrict__ wsb) {
  __shared__ __align__(16) float pv[256];
  int bi = blockIdx.x;                       // b*85 + pos
  int b = bi / 85, pos = bi % 85;
  int d = (pos < 64) ? 3 : (pos < 80) ? 2 : (pos < 84) ? 1 : 0;
  int t = threadIdx.x;
  pv[t] = wsb[WS_PALL + (size_t)(b*NCH + t)*POS + pos];
  __syncthreads();
  const float* wrow = wconv + ((size_t)d*NCH + t)*NCH;
  float acc = 0.f;
  #pragma unroll 4
  for (int c4 = 0; c4 < 64; c4++) {
    f32x4 wv = *(const f32x4*)(wrow + c4*4);
    f32x4 xv = *(const f32x4*)(&pv[c4*4]);
    acc += wv.x*xv.x + wv.y*xv.y + wv.z*xv.z + wv.w*xv.w;
  }
  wsb[WS_YD + (size_t)(b*NCH + t)*POS + pos] = acc;
  atomicAdd(&wsb[WS_PSUM + d*NCH + t], acc);
  atomicAdd(&wsb[WS_PSQ  + d*NCH + t], acc*acc);
}

// K3: contrib[b][o][cell] = sum over all 4 depths (no atomics; grid = 64 cells)
__global__ __launch_bounds__(256) void k_contrib(const float* __restrict__ wf,
                                                 const float* __restrict__ gs,
                                                 const float* __restrict__ bs,
                                                 float* __restrict__ wsb) {
  __shared__ __align__(16) float pn[16][256];   // [d*4+b][c]
  int cell = blockIdx.x;
  int by = cell >> 3, bx = cell & 7;
  int t = threadIdx.x;
  #pragma unroll
  for (int d = 0; d < 4; d++) {
    int pos = (d == 3) ? cell
            : (d == 2) ? 64 + (by >> 1)*4 + (bx >> 1)
            : (d == 1) ? 80 + (by >> 2)*2 + (bx >> 2)
            : 84;
    float cnt = (float)(4 << (2*d));
    float mu  = wsb[WS_PSUM + d*NCH + t] / cnt;
    float var = wsb[WS_PSQ  + d*NCH + t] / cnt - mu*mu;
    float sc  = gs[d*NCH + t] * rsqrtf(var + BN_EPS);
    float bi_ = bs[d*NCH + t] - mu * sc;
    #pragma unroll
    for (int b = 0; b < 4; b++)
      pn[d*4 + b][t] = wsb[WS_YD + (size_t)(b*NCH + t)*POS + pos] * sc + bi_;
  }
  __syncthreads();
  float a0 = 0.f, a1 = 0.f, a2 = 0.f, a3 = 0.f;
  #pragma unroll
  for (int d = 0; d < 4; d++) {
    const float* wrow = wf + (size_t)t*1280 + 256 + d*256;
    #pragma unroll 4
    for (int j = 0; j < 64; j++) {
      f32x4 wv = *(const f32x4*)(wrow + j*4);
      f32x4 p0 = *(const f32x4*)(&pn[d*4 + 0][j*4]);
      f32x4 p1 = *(const f32x4*)(&pn[d*4 + 1][j*4]);
      f32x4 p2 = *(const f32x4*)(&pn[d*4 + 2][j*4]);
      f32x4 p3 = *(const f32x4*)(&pn[d*4 + 3][j*4]);
      a0 += wv.x*p0.x + wv.y*p0.y + wv.z*p0.z + wv.w*p0.w;
      a1 += wv.x*p1.x + wv.y*p1.y + wv.z*p1.z + wv.w*p1.w;
      a2 += wv.x*p2.x + wv.y*p2.y + wv.z*p2.z + wv.w*p2.w;
      a3 += wv.x*p3.x + wv.y*p3.y + wv.z*p3.z + wv.w*p3.w;
    }
  }
  wsb[WS_CONTRIB + (size_t)(0*NCH + t)*64 + cell] = a0;
  wsb[WS_CONTRIB + (size_t)(1*NCH + t)*64 + cell] = a1;
  wsb[WS_CONTRIB + (size_t)(2*NCH + t)*64 + cell] = a2;
  wsb[WS_CONTRIB + (size_t)(3*NCH + t)*64 + cell] = a3;
}

// K4: main GEMM (r7 structure), 2-slab phases: 4 barriers total, no sched_barrier,
//     LDS union (phase buffers / ytile). Epilogue: r7 coalesced LDS-bounce.
template<bool YBF>
__global__ __launch_bounds__(256, 3) void k_main(const float* __restrict__ x,
                                                 float* __restrict__ wsb, float* __restrict__ y) {
  __shared__ __align__(16) char smem[40960];     // union: xbuf 2x10240B | ytile 36864B
  __shared__ float ctile[256*4];                 // 4 KB
  u32* xbuf = (u32*)smem;                        // [buf][px*40 u32]
  int wg = blockIdx.x;
  int b = wg / 576, tile = wg % 576;
  int n0 = tile * 64;
  int t = threadIdx.x, w = t >> 6, l = t & 63, g = l >> 4, ln = l & 15;
  int cb0 = (tile % 3) * 64;
  int rowblk = (tile / 3) / 24;
  int cblk0 = cb0 / 24;
  const u16* wpk = (const u16*)(wsb + WS_WPK);
  int mrow = w*64 + ln;
  int qq = t & 15, c2 = t >> 4;                  // staging: px-quad, channel-pair
  const float* xsrc = x + (size_t)(b*NCH + 2*c2)*HW + n0 + 4*qq;

  // ctile global loads (issued first)
  float ct[4];
  {
    const float* cbase = wsb + WS_CONTRIB + ((size_t)b*NCH + t)*64 + rowblk*8;
    #pragma unroll
    for (int i = 0; i < 4; i++) {
      int cc = cblk0 + i; if (cc > 7) cc = 7;
      ct[i] = cbase[cc];
    }
  }
  // prologue: x loads for phases 0,1 (slabs 0..3) -> 8 f32x4 in flight
  f32x4 xr[2][2][2];                             // [phase parity][slab-in-phase][half]
  #pragma unroll
  for (int pp = 0; pp < 2; pp++)
    #pragma unroll
    for (int s = 0; s < 2; s++)
      #pragma unroll
      for (int h = 0; h < 2; h++)
        xr[pp][s][h] = *(const f32x4*)(xsrc + (size_t)((pp*2 + s)*32 + h)*HW);

  #pragma unroll
  for (int i = 0; i < 4; i++) ctile[t*4 + i] = ct[i];
  asm volatile("s_waitcnt lgkmcnt(0)" ::: "memory");
  __builtin_amdgcn_s_barrier();

  f32x4 acc[4][4];
  #pragma unroll
  for (int i = 0; i < 4; i++)
    #pragma unroll
    for (int j = 0; j < 4; j++)
      acc[i][j] = {0.f, 0.f, 0.f, 0.f};

  int slot = (((c2 >> 2) ^ (qq & 3)) << 2) | (c2 & 3);   // group-XOR swizzle

  #pragma unroll
  for (int p = 0; p < 4; p++) {
    // stage phase p (slabs 2p, 2p+1) into buf[p&1]
    {
      u32* dst = xbuf + (p & 1)*2560;
      #pragma unroll
      for (int s = 0; s < 2; s++) {
        f32x4 va = xr[p & 1][s][0], vb = xr[p & 1][s][1];
        #pragma unroll
        for (int j = 0; j < 4; j++) {
          u32 pk = (u32)f2bf(va[j]) | ((u32)f2bf(vb[j]) << 16);
          dst[(4*qq + j)*40 + s*20 + slot] = pk;
        }
      }
    }
    asm volatile("s_waitcnt lgkmcnt(0)" ::: "memory");
    __builtin_amdgcn_s_barrier();
    // prefetch x for phase p+2
    if (p < 2) {
      #pragma unroll
      for (int s = 0; s < 2; s++)
        #pragma unroll
        for (int h = 0; h < 2; h++)
          xr[p & 1][s][h] = *(const f32x4*)(xsrc + (size_t)(((p+2)*2 + s)*32 + h)*HW);
    }
    // compute both slabs of phase p
    #pragma unroll
    for (int s = 0; s < 2; s++) {
      int sl = p*2 + s;
      s16x8 af[4];
      #pragma unroll
      for (int tm = 0; tm < 4; tm++)
        af[tm] = *(const s16x8*)(wpk + ((size_t)(sl*4 + g)*256 + mrow + tm*16)*8);
      const u32* xb = xbuf + (p & 1)*2560 + s*20;
      #pragma unroll
      for (int tn = 0; tn < 4; tn++) {
        int px = 16*tn + ln;
        int gr = g ^ ((px >> 2) & 3);
        s16x8 bfr = *(const s16x8*)((const u16*)&xb[px*40 + gr*4]);
        #pragma unroll
        for (int tm = 0; tm < 4; tm++)
          acc[tm][tn] = __builtin_amdgcn_mfma_f32_16x16x32_bf16(af[tm], bfr, acc[tm][tn], 0, 0, 0);
      }
    }
  }

  // epilogue: add contrib, stats, bf16 into ytile (union: wait for all LDS readers)
  __syncthreads();
  u16* ytile = (u16*)smem;                       // [256 o][72 px pitch]
  int ci[4];
  #pragma unroll
  for (int tn = 0; tn < 4; tn++)
    ci[tn] = (cb0 + 16*tn + ln)/24 - cblk0;
  int bkt = wg & (NBKT - 1);
  float* fsum = wsb + WS_FSUMB + bkt*256;
  float* fsq  = wsb + WS_FSQB  + bkt*256;
  float* yf   = y + (size_t)b*NCH*HW + n0;
  #pragma unroll
  for (int tm = 0; tm < 4; tm++) {
    #pragma unroll
    for (int r = 0; r < 4; r++) {
      int o = w*64 + tm*16 + g*4 + r;
      float s1 = 0.f, s2 = 0.f;
      #pragma unroll
      for (int tn = 0; tn < 4; tn++) {
        int px = 16*tn + ln;
        float v = acc[tm][tn][r] + ctile[o*4 + ci[tn]];
        if (YBF) {
          u16 h = f2bf(v);
          ytile[o*72 + px] = h;
          float yr = bf2f(h);
          s1 += yr; s2 += yr*yr;
        } else {
          yf[(size_t)o*HW + px] = v;
          s1 += v; s2 += v*v;
        }
      }
      s1 += __shfl_xor(s1, 1);  s2 += __shfl_xor(s2, 1);
      s1 += __shfl_xor(s1, 2);  s2 += __shfl_xor(s2, 2);
      s1 += __shfl_xor(s1, 4);  s2 += __shfl_xor(s2, 4);
      s1 += __shfl_xor(s1, 8);  s2 += __shfl_xor(s2, 8);
      if (ln == 0) { atomicAdd(&fsum[o], s1); atomicAdd(&fsq[o], s2); }
    }
  }
  if (YBF) {
    __syncthreads();
    // coalesced store: 8 rounds; lane = (o' = t>>3 within 32-o group, seg = t&7)
    u16* ybb = (u16*)(wsb + WS_YBF) + (size_t)b*NCH*HW + n0;
    int oo = t >> 3, seg = t & 7;
    #pragma unroll
    for (int r8 = 0; r8 < 8; r8++) {
      int o = r8*32 + oo;
      u16x8 v = *(const u16x8*)(&ytile[o*72 + seg*8]);
      *(u16x8*)(ybb + (size_t)o*HW + seg*8) = v;
    }
  }
}

// K5: normalize with inline final BN stats (r2-proven coalesced shape)
template<bool YBF>
__global__ __launch_bounds__(256) void k_norm(float* __restrict__ out,
                                              const float* __restrict__ gf,
                                              const float* __restrict__ bfv,
                                              const float* __restrict__ wsb) {
  int bid = blockIdx.x;                      // plane*4 + quarter
  int plane = bid >> 2, q = bid & 3;
  int c = plane & 255;
  float s1 = 0.f, s2 = 0.f;
  #pragma unroll
  for (int i = 0; i < NBKT; i++) {
    s1 += wsb[WS_FSUMB + i*256 + c];
    s2 += wsb[WS_FSQB  + i*256 + c];
  }
  float inv = 1.f / (float)NPIX;
  float mu  = s1 * inv;
  float var = s2 * inv - mu*mu;
  float sc  = gf[c] * rsqrtf(var + BN_EPS);
  float bi  = bfv[c] - mu * sc;
  size_t base4 = ((size_t)plane*HW + q*(HW/4)) >> 2;   // f32x4 / u16x4 index
  int t = threadIdx.x;
  if (YBF) {
    const u16* yb = (const u16*)(wsb + WS_YBF);
    #pragma unroll
    for (int it = 0; it < 9; it++) {
      size_t i4 = base4 + it*256 + t;
      u16x4 v = *(const u16x4*)(yb + i4*4);
      f32x4 o;
      o.x = bf2f(v[0])*sc + bi;
      o.y = bf2f(v[1])*sc + bi;
      o.z = bf2f(v[2])*sc + bi;
      o.w = bf2f(v[3])*sc + bi;
      ((f32x4*)out)[i4] = o;
    }
  } else {
    #pragma unroll
    for (int it = 0; it < 9; it++) {
      size_t i4 = base4 + it*256 + t;
      f32x4 v = ((f32x4*)out)[i4];
      v.x = v.x*sc + bi; v.y = v.y*sc + bi; v.z = v.z*sc + bi; v.w = v.w*sc + bi;
      ((f32x4*)out)[i4] = v;
    }
  }
}

extern "C" void kernel_launch(void* const* d_in, const int* in_sizes, int n_in,
                              void* d_out, int out_size, void* d_ws, size_t ws_size,
                              hipStream_t stream) {
  const float* x  = (const float*)d_in[0];
  const float* w  = (const float*)d_in[1];
  const float* gs = (const float*)d_in[2];
  const float* bs = (const float*)d_in[3];
  const float* wf = (const float*)d_in[4];
  const float* gf = (const float*)d_in[5];
  const float* bf = (const float*)d_in[6];
  float* y   = (float*)d_out;
  float* wsb = (float*)d_ws;

  bool ybf = ws_size >= (size_t)WS_TOT1 * sizeof(float);

  k_pool   <<<1068, 192, 0, stream>>>(x, wf, wsb);
  k_pyr    <<<NB*POS, 256, 0, stream>>>(w, wsb);
  k_contrib<<<64, 256, 0, stream>>>(wf, gs, bs, wsb);
  if (ybf) k_main<true> <<<NB*576, 256, 0, stream>>>(x, wsb, y);
  else     k_main<false><<<NB*576, 256, 0, stream>>>(x, wsb, y);
  if (ybf) k_norm<true> <<<4096, 256, 0, stream>>>(y, gf, bf, wsb);
  else     k_norm<false><<<4096, 256, 0, stream>>>(y, gf, bf, wsb);
}